// Round 4
// baseline (739.917 us; speedup 1.0000x reference)
//
#include <hip/hip_runtime.h>
#include <hip/hip_cooperative_groups.h>

namespace cg = cooperative_groups;

// CapsNet dynamic routing — single cooperative kernel, pred never materialized.
// Phases separated by grid.sync():
//   P0 (block=batch): x->fp16 (both orientations), W->fp16 (both), b_init->LDS
//   P1 (block=batch): [delta = u@xT (MFMA), b += delta+vb (LDS-resident)]
//                     softmax(b) -> c ; y = c@x (MFMA) -> y16 global
//   P2 (block=(j, 32-batch chunk)): s = y@W^T (MFMA) + bias*csum ;
//                     v = squash(s) ; u = v@WT (MFMA) ; vb = v.bias
// 3 iterations; r==2 stops at v -> d_out. b never touches global memory.

#define BSZ 256
#define CDIM 256
#define IDIM 256
#define JDIM 32
#define DDIM 64

typedef _Float16 f16x8 __attribute__((ext_vector_type(8)));
typedef _Float16 f16x4 __attribute__((ext_vector_type(4)));
typedef float f32x4 __attribute__((ext_vector_type(4)));

__global__ __launch_bounds__(512, 2) void caps_mega(
    const float* __restrict__ x,       // [BSZ][CDIM][IDIM]
    const float* __restrict__ W,       // [JDIM*DDIM][CDIM]
    const float* __restrict__ bias,    // [JDIM*DDIM]
    const float* __restrict__ b_init,  // [BSZ][JDIM][IDIM]
    _Float16* __restrict__ x16,        // [BSZ][CDIM][IDIM]
    _Float16* __restrict__ xT16,       // [BSZ][IDIM][CDIM]
    _Float16* __restrict__ W16,        // [JDIM][DDIM][CDIM]
    _Float16* __restrict__ WT16,       // [JDIM][CDIM][DDIM]
    _Float16* __restrict__ y16,        // [BSZ][JDIM][CDIM]
    _Float16* __restrict__ u16,        // [BSZ][JDIM][CDIM]
    float* __restrict__ csum_ws,       // [BSZ][JDIM]
    float* __restrict__ vb_ws,         // [BSZ][JDIM]
    float* __restrict__ vout)          // [BSZ][JDIM][DDIM]
{
  cg::grid_group gg = cg::this_grid();

  __shared__ __align__(16) float bsh[JDIM * 264];   // 33792 B, persists all 3 iters
  __shared__ __align__(16) char un[30720];          // time-multiplexed region
  // P1 views:
  _Float16* uc   = (_Float16*)un;                   // [32*264] us (delta) then cs (softmax/y)
  float*    vbs  = (float*)(un + 16896);            // [32]
  // P2 views (time-disjoint from P1 views):
  _Float16* y16s = (_Float16*)un;                   // [32*264]
  float*    ssh  = (float*)(un + 16896);            // [32*68]
  _Float16* vsh  = (_Float16*)(un + 25600);         // [32*72]
  float*    bjs  = (float*)(un + 30208);            // [64]
  float*    csms = (float*)(un + 30464);            // [32]

  const int b = blockIdx.x;
  const int t = threadIdx.x;
  const int w = t >> 6, lane = t & 63, l15 = lane & 15, quad = lane >> 4;

  // ---------------- P0: conversions + b_init -> LDS ----------------
  {
    const float* xb = x + (size_t)b * 65536;
    _Float16* x16b = x16 + (size_t)b * 65536;
    _Float16* xTb  = xT16 + (size_t)b * 65536;
    for (int q = 0; q < 8; ++q) {
      const int c0 = q * 32;
      const int c4 = (t & 7) * 4;
      const int i4 = (t >> 3) * 4;
      f32x4 v[4];
      #pragma unroll
      for (int s = 0; s < 4; ++s)
        v[s] = *reinterpret_cast<const f32x4*>(&xb[(c0 + c4 + s) * 256 + i4]);
      #pragma unroll
      for (int s = 0; s < 4; ++s) {
        f16x4 h;
        h[0] = (_Float16)v[s][0]; h[1] = (_Float16)v[s][1];
        h[2] = (_Float16)v[s][2]; h[3] = (_Float16)v[s][3];
        *reinterpret_cast<f16x4*>(&x16b[(c0 + c4 + s) * 256 + i4]) = h;
      }
      #pragma unroll
      for (int m = 0; m < 4; ++m) {
        f16x4 h;
        h[0] = (_Float16)v[0][m]; h[1] = (_Float16)v[1][m];
        h[2] = (_Float16)v[2][m]; h[3] = (_Float16)v[3][m];
        *reinterpret_cast<f16x4*>(&xTb[(i4 + m) * 256 + c0 + c4]) = h;
      }
    }
    // W: 2048 rows; block b converts rows b*8 .. b*8+7
    {
      const int row = b * 8 + (t >> 6);
      const int c4 = (t & 63) * 4;
      const int j = row >> 6, d = row & 63;
      f32x4 wv = *reinterpret_cast<const f32x4*>(&W[(size_t)row * 256 + c4]);
      f16x4 h;
      h[0] = (_Float16)wv[0]; h[1] = (_Float16)wv[1];
      h[2] = (_Float16)wv[2]; h[3] = (_Float16)wv[3];
      *reinterpret_cast<f16x4*>(&W16[((size_t)j * 64 + d) * 256 + c4]) = h;
      #pragma unroll
      for (int s = 0; s < 4; ++s)
        WT16[((size_t)j * 256 + c4 + s) * 64 + d] = h[s];
    }
    // b_init -> bsh
    #pragma unroll
    for (int q = 0; q < 4; ++q) {
      const int e = q * 2048 + t * 4;
      const int j = e >> 8, i4 = e & 255;
      *reinterpret_cast<f32x4*>(&bsh[j * 264 + i4]) =
          *reinterpret_cast<const f32x4*>(&b_init[(size_t)b * 8192 + e]);
    }
  }
  __threadfence();
  gg.sync();

  const int jb = b & 31;
  const int b0 = (b >> 5) * 32;

  for (int r = 0; r < 3; ++r) {
    // ---------------- P1 (per-batch b) ----------------
    if (r) {
      const int* ug = reinterpret_cast<const int*>(u16 + (size_t)b * 8192);
      for (int p = t; p < 4096; p += 512) {
        int j = p >> 7, c2 = p & 127;
        *reinterpret_cast<int*>(&uc[j * 264 + c2 * 2]) = ug[p];
      }
      if (t < 32) vbs[t] = vb_ws[b * 32 + t];
      __syncthreads();

      const _Float16* xTb = xT16 + (size_t)b * 65536;
      f32x4 acc[2][2];
      #pragma unroll
      for (int mt = 0; mt < 2; ++mt)
        #pragma unroll
        for (int nt = 0; nt < 2; ++nt) acc[mt][nt] = (f32x4){0.f, 0.f, 0.f, 0.f};
      const int ibase = w * 32;
      for (int k0 = 0; k0 < 256; k0 += 32) {
        const int ko = k0 + quad * 8;
        f16x8 a0 = *reinterpret_cast<const f16x8*>(&uc[l15 * 264 + ko]);
        f16x8 a1 = *reinterpret_cast<const f16x8*>(&uc[(16 + l15) * 264 + ko]);
        #pragma unroll
        for (int nt = 0; nt < 2; ++nt) {
          const int ii = ibase + nt * 16 + l15;
          f16x8 bf = *reinterpret_cast<const f16x8*>(&xTb[ii * 256 + ko]);
          acc[0][nt] = __builtin_amdgcn_mfma_f32_16x16x32_f16(a0, bf, acc[0][nt], 0, 0, 0);
          acc[1][nt] = __builtin_amdgcn_mfma_f32_16x16x32_f16(a1, bf, acc[1][nt], 0, 0, 0);
        }
      }
      #pragma unroll
      for (int mt = 0; mt < 2; ++mt)
        #pragma unroll
        for (int nt = 0; nt < 2; ++nt) {
          const int ii = ibase + nt * 16 + l15;
          #pragma unroll
          for (int rr = 0; rr < 4; ++rr) {
            const int j = mt * 16 + quad * 4 + rr;
            bsh[j * 264 + ii] += acc[mt][nt][rr] + vbs[j];
          }
        }
      __syncthreads();
    }

    // softmax over j (column i = t), from LDS-resident b
    if (t < 256) {
      float bv[JDIM];
      #pragma unroll
      for (int j = 0; j < JDIM; ++j) bv[j] = bsh[j * 264 + t];
      float m = bv[0];
      #pragma unroll
      for (int j = 1; j < JDIM; ++j) m = fmaxf(m, bv[j]);
      float s = 0.f;
      #pragma unroll
      for (int j = 0; j < JDIM; ++j) { bv[j] = __expf(bv[j] - m); s += bv[j]; }
      float rs = 1.f / s;
      #pragma unroll
      for (int j = 0; j < JDIM; ++j) uc[j * 264 + t] = (_Float16)(bv[j] * rs);
    }
    __syncthreads();

    // csum[j]
    if (t < 256) {
      const int j = t >> 3, ig = t & 7;
      float su = 0.f;
      #pragma unroll
      for (int s8 = 0; s8 < 32; s8 += 8) {
        f16x8 vv = *reinterpret_cast<const f16x8*>(&uc[j * 264 + ig * 32 + s8]);
        #pragma unroll
        for (int k = 0; k < 8; ++k) su += (float)vv[k];
      }
      su += __shfl_xor(su, 1);
      su += __shfl_xor(su, 2);
      su += __shfl_xor(su, 4);
      if (ig == 0) csum_ws[b * 32 + j] = su;
    }

    // y[j,c] = sum_i c[j,i] * x16[c,i]  -> y16 global (fp16)
    {
      const _Float16* xbg = x16 + (size_t)b * 65536;
      f32x4 acy[2][2];
      #pragma unroll
      for (int mt = 0; mt < 2; ++mt)
        #pragma unroll
        for (int nt = 0; nt < 2; ++nt) acy[mt][nt] = (f32x4){0.f, 0.f, 0.f, 0.f};
      const int cbase = w * 32;
      for (int k0 = 0; k0 < 256; k0 += 32) {
        const int ko = k0 + quad * 8;
        f16x8 a0 = *reinterpret_cast<const f16x8*>(&uc[l15 * 264 + ko]);
        f16x8 a1 = *reinterpret_cast<const f16x8*>(&uc[(16 + l15) * 264 + ko]);
        #pragma unroll
        for (int nt = 0; nt < 2; ++nt) {
          const int cp = cbase + nt * 16 + l15;
          f16x8 bf = *reinterpret_cast<const f16x8*>(&xbg[cp * 256 + ko]);
          acy[0][nt] = __builtin_amdgcn_mfma_f32_16x16x32_f16(a0, bf, acy[0][nt], 0, 0, 0);
          acy[1][nt] = __builtin_amdgcn_mfma_f32_16x16x32_f16(a1, bf, acy[1][nt], 0, 0, 0);
        }
      }
      _Float16* yb = y16 + (size_t)b * 8192;
      #pragma unroll
      for (int mt = 0; mt < 2; ++mt)
        #pragma unroll
        for (int nt = 0; nt < 2; ++nt) {
          const int cp = cbase + nt * 16 + l15;
          #pragma unroll
          for (int rr = 0; rr < 4; ++rr)
            yb[(mt * 16 + quad * 4 + rr) * 256 + cp] = (_Float16)acy[mt][nt][rr];
        }
    }
    __threadfence();
    gg.sync();

    // ---------------- P2 (per (jb, 32-batch chunk)) ----------------
    for (int uu = t; uu < 1024; uu += 512) {
      const int bs_ = uu >> 5, off = (uu & 31) * 8;
      *reinterpret_cast<f16x8*>(&y16s[bs_ * 264 + off]) =
          *reinterpret_cast<const f16x8*>(&y16[(size_t)(b0 + bs_) * 8192 + jb * 256 + off]);
    }
    if (t < 64) bjs[t] = bias[jb * 64 + t];
    if (t < 32) csms[t] = csum_ws[(b0 + t) * 32 + jb];
    __syncthreads();

    // s-GEMM: S[32 bs, 64 d] = Y[32, 256c] * W_j[d, c]^T
    {
      const int mt = w & 1, nt = w >> 1;
      const _Float16* Wg = W16 + (size_t)jb * 16384;
      f32x4 sacc = (f32x4){0.f, 0.f, 0.f, 0.f};
      for (int k0 = 0; k0 < 256; k0 += 32) {
        const int ko = k0 + quad * 8;
        f16x8 a = *reinterpret_cast<const f16x8*>(&y16s[(mt * 16 + l15) * 264 + ko]);
        f16x8 bf = *reinterpret_cast<const f16x8*>(&Wg[(nt * 16 + l15) * 256 + ko]);
        sacc = __builtin_amdgcn_mfma_f32_16x16x32_f16(a, bf, sacc, 0, 0, 0);
      }
      #pragma unroll
      for (int rr = 0; rr < 4; ++rr) {
        const int bs_ = mt * 16 + quad * 4 + rr, d = nt * 16 + l15;
        ssh[bs_ * 68 + d] = sacc[rr] + bjs[d] * csms[bs_];
      }
    }
    __syncthreads();

    // squash -> v (and vout at r==2), vb
    if (t < 256) {
      const int bs_ = t >> 3, dg = t & 7;
      float sv[8];
      float n2 = 0.f;
      #pragma unroll
      for (int k = 0; k < 8; ++k) {
        sv[k] = ssh[bs_ * 68 + dg * 8 + k];
        n2 += sv[k] * sv[k];
      }
      n2 += __shfl_xor(n2, 1);
      n2 += __shfl_xor(n2, 2);
      n2 += __shfl_xor(n2, 4);
      const float sc = sqrtf(n2) / (1.f + n2);
      if (r == 2) {
        float* vp = vout + ((size_t)(b0 + bs_) * 32 + jb) * 64 + dg * 8;
        #pragma unroll
        for (int k = 0; k < 8; ++k) vp[k] = sv[k] * sc;
      } else {
        float vbp = 0.f;
        #pragma unroll
        for (int k = 0; k < 8; ++k) {
          const float vv = sv[k] * sc;
          vsh[bs_ * 72 + dg * 8 + k] = (_Float16)vv;
          vbp += vv * bjs[dg * 8 + k];
        }
        vbp += __shfl_xor(vbp, 1);
        vbp += __shfl_xor(vbp, 2);
        vbp += __shfl_xor(vbp, 4);
        if (dg == 0) vb_ws[(b0 + bs_) * 32 + jb] = vbp;
      }
    }

    if (r < 2) {
      __syncthreads();
      // u-GEMM: U[32 bs, 256 c] = V[32, 64d] * WT_j[c, d]^T
      const int mt = w & 1, ng = (w >> 1) * 4;
      const _Float16* WTg = WT16 + (size_t)jb * 16384;
      #pragma unroll
      for (int nn = 0; nn < 4; ++nn) {
        f32x4 ua = (f32x4){0.f, 0.f, 0.f, 0.f};
        #pragma unroll
        for (int k0 = 0; k0 < 64; k0 += 32) {
          const int ko = k0 + quad * 8;
          f16x8 a = *reinterpret_cast<const f16x8*>(&vsh[(mt * 16 + l15) * 72 + ko]);
          f16x8 bf = *reinterpret_cast<const f16x8*>(&WTg[((ng + nn) * 16 + l15) * 64 + ko]);
          ua = __builtin_amdgcn_mfma_f32_16x16x32_f16(a, bf, ua, 0, 0, 0);
        }
        #pragma unroll
        for (int rr = 0; rr < 4; ++rr) {
          const int bs_ = mt * 16 + quad * 4 + rr;
          const int cc = (ng + nn) * 16 + l15;
          u16[(size_t)(b0 + bs_) * 8192 + jb * 256 + cc] = (_Float16)ua[rr];
        }
      }
      __threadfence();
      gg.sync();
    }
  }
}

// ---------------------------------------------------------------------------
extern "C" void kernel_launch(void* const* d_in, const int* in_sizes, int n_in,
                              void* d_out, int out_size, void* d_ws, size_t ws_size,
                              hipStream_t stream) {
  (void)in_sizes; (void)n_in; (void)out_size; (void)ws_size;
  const float* x      = (const float*)d_in[0];
  const float* W      = (const float*)d_in[1];
  const float* bias   = (const float*)d_in[2];
  const float* b_init = (const float*)d_in[3];
  char* ws = (char*)d_ws;

  _Float16* x16     = (_Float16*)(ws);                            // 32 MiB
  _Float16* xT16    = (_Float16*)(ws + (32u << 20));              // 32 MiB
  _Float16* W16     = (_Float16*)(ws + (64u << 20));              // 1 MiB
  _Float16* WT16    = (_Float16*)(ws + (65u << 20));              // 1 MiB
  _Float16* y16     = (_Float16*)(ws + (66u << 20));              // 4 MiB
  _Float16* u16     = (_Float16*)(ws + (70u << 20));              // 4 MiB
  float*    csum_ws = (float*)(ws + (74u << 20));                 // 32 KiB
  float*    vb_ws   = (float*)(ws + (74u << 20) + (64u << 10));   // 32 KiB
  float*    vout    = (float*)d_out;

  void* args[] = {&x, &W, &bias, &b_init, &x16, &xT16, &W16, &WT16,
                  &y16, &u16, &csum_ws, &vb_ws, &vout};
  hipLaunchCooperativeKernel((const void*)caps_mega, dim3(BSZ), dim3(512),
                             (void**)args, 0, stream);
}

// Round 5
// 429.695 us; speedup vs baseline: 1.7220x; 1.7220x over previous
//
#include <hip/hip_runtime.h>

// CapsNet dynamic routing — per-batch-independent formulation, 2 launches,
// ZERO grid syncs (R4's cooperative version spent 99% idle in fence/sync).
//   prep_w:       W fp32 -> W16 [j*64+d][c] and WT16 [j*256+c][d] (fp16)
//   caps_routing: block = batch. Converts its x slice to fp16 (both
//     orientations) once, then 3 routing iterations entirely in-block:
//       delta = u@xT (MFMA) ; b += delta+vb  (b in REGISTERS, D-layout)
//       softmax over j via shfl_xor(16/32) across quads ; c -> LDS
//       y = c@x (MFMA) -> LDS ; s = W16.y (VALU, W from L2) + bias*csum
//       v = squash(s) ; u = v.WT16 (VALU) -> LDS ; loop
//     W16+WT16 = 2 MB fp16 fits each XCD's 4 MB L2 -> re-reads are L2 hits.

#define BSZ 256
#define CDIM 256
#define IDIM 256
#define JDIM 32
#define DDIM 64

typedef _Float16 f16x8 __attribute__((ext_vector_type(8)));
typedef _Float16 f16x4 __attribute__((ext_vector_type(4)));
typedef float f32x4 __attribute__((ext_vector_type(4)));

// ---------------------------------------------------------------------------
__global__ __launch_bounds__(256) void prep_w(
    const float* __restrict__ W,
    _Float16* __restrict__ W16,
    _Float16* __restrict__ WT16)
{
  const int p = (blockIdx.x * 256 + threadIdx.x) * 4;  // grid 512 -> 524288 elems
  const int row = p >> 8, c = p & 255;
  const int j = row >> 6, d = row & 63;
  f32x4 wv = *reinterpret_cast<const f32x4*>(&W[p]);
  f16x4 h;
  h[0] = (_Float16)wv[0]; h[1] = (_Float16)wv[1];
  h[2] = (_Float16)wv[2]; h[3] = (_Float16)wv[3];
  *reinterpret_cast<f16x4*>(&W16[p]) = h;
  #pragma unroll
  for (int s = 0; s < 4; ++s)
    WT16[((size_t)j * 256 + c + s) * 64 + d] = h[s];
}

// ---------------------------------------------------------------------------
__global__ __launch_bounds__(512) void caps_routing(
    const float* __restrict__ x,       // [BSZ][CDIM][IDIM] fp32
    const float* __restrict__ bias,    // [JDIM*DDIM] fp32
    const float* __restrict__ b_init,  // [BSZ][JDIM][IDIM] fp32
    const _Float16* __restrict__ W16,  // [JDIM*DDIM][CDIM]
    const _Float16* __restrict__ WT16, // [JDIM*CDIM][DDIM]
    _Float16* __restrict__ x16,        // ws [BSZ][CDIM][IDIM]
    _Float16* __restrict__ xT16,       // ws [BSZ][IDIM][CDIM]
    float* __restrict__ vout)          // [BSZ][JDIM][DDIM]
{
  // R1: cs (softmax..y-GEMM)  UNION  ush (u-phase..next delta)   [time-disjoint]
  // R2: ysh (y-epilogue..s-phase) UNION vsh f32 (squash..u-phase)
  __shared__ __align__(16) _Float16 R1[JDIM * 264];   // 16896 B
  __shared__ __align__(16) _Float16 R2[JDIM * 264];   // 16896 B
  __shared__ float csumsh[JDIM];
  __shared__ float vbs[JDIM];
  float* vsh = reinterpret_cast<float*>(R2);          // 32*68 f32 = 8704 B

  const int b = blockIdx.x, t = threadIdx.x;
  const int w = t >> 6, lane = t & 63, l15 = lane & 15, quad = lane >> 4;

  // ---- convert own x slice to fp16, both orientations (once) ----
  {
    const float* xb = x + (size_t)b * 65536;
    _Float16* xo = x16 + (size_t)b * 65536;
    _Float16* xto = xT16 + (size_t)b * 65536;
    const int c4 = (t & 7) * 4, i4 = (t >> 3) * 4;
    for (int q = 0; q < 8; ++q) {
      const int c0 = q * 32 + c4;
      f32x4 v[4];
      #pragma unroll
      for (int s = 0; s < 4; ++s)
        v[s] = *reinterpret_cast<const f32x4*>(&xb[(c0 + s) * 256 + i4]);
      #pragma unroll
      for (int s = 0; s < 4; ++s) {
        f16x4 h;
        h[0] = (_Float16)v[s][0]; h[1] = (_Float16)v[s][1];
        h[2] = (_Float16)v[s][2]; h[3] = (_Float16)v[s][3];
        *reinterpret_cast<f16x4*>(&xo[(c0 + s) * 256 + i4]) = h;
      }
      #pragma unroll
      for (int m = 0; m < 4; ++m) {
        f16x4 h;
        h[0] = (_Float16)v[0][m]; h[1] = (_Float16)v[1][m];
        h[2] = (_Float16)v[2][m]; h[3] = (_Float16)v[3][m];
        *reinterpret_cast<f16x4*>(&xto[(i4 + m) * 256 + c0]) = h;
      }
    }
  }

  // ---- b -> registers in MFMA D-layout: breg[mt][nt][rr] = b[j][ii],
  //      j = mt*16+quad*4+rr, ii = w*32+nt*16+l15 ----
  float breg[2][2][4];
  {
    const float* bp = b_init + (size_t)b * 8192;
    #pragma unroll
    for (int mt = 0; mt < 2; ++mt)
      #pragma unroll
      for (int nt = 0; nt < 2; ++nt)
        #pragma unroll
        for (int rr = 0; rr < 4; ++rr)
          breg[mt][nt][rr] =
              bp[(mt * 16 + quad * 4 + rr) * 256 + w * 32 + nt * 16 + l15];
  }
  __syncthreads();

  const _Float16* xob = x16 + (size_t)b * 65536;
  const _Float16* xtb = xT16 + (size_t)b * 65536;

  for (int r = 0; r < 3; ++r) {
    if (r) {
      // ---- delta[j,ii] = sum_c u[j,c] * xT[ii,c]  (A from R1=ush) ----
      f32x4 acc[2][2];
      #pragma unroll
      for (int mt = 0; mt < 2; ++mt)
        #pragma unroll
        for (int nt = 0; nt < 2; ++nt) acc[mt][nt] = (f32x4){0.f, 0.f, 0.f, 0.f};
      const int ibase = w * 32;
      for (int k0 = 0; k0 < 256; k0 += 32) {
        const int ko = k0 + quad * 8;
        f16x8 a0 = *reinterpret_cast<const f16x8*>(&R1[l15 * 264 + ko]);
        f16x8 a1 = *reinterpret_cast<const f16x8*>(&R1[(16 + l15) * 264 + ko]);
        #pragma unroll
        for (int nt = 0; nt < 2; ++nt) {
          const int ii = ibase + nt * 16 + l15;
          f16x8 bf = *reinterpret_cast<const f16x8*>(&xtb[ii * 256 + ko]);
          acc[0][nt] = __builtin_amdgcn_mfma_f32_16x16x32_f16(a0, bf, acc[0][nt], 0, 0, 0);
          acc[1][nt] = __builtin_amdgcn_mfma_f32_16x16x32_f16(a1, bf, acc[1][nt], 0, 0, 0);
        }
      }
      #pragma unroll
      for (int mt = 0; mt < 2; ++mt)
        #pragma unroll
        for (int nt = 0; nt < 2; ++nt)
          #pragma unroll
          for (int rr = 0; rr < 4; ++rr)
            breg[mt][nt][rr] += acc[mt][nt][rr] + vbs[mt * 16 + quad * 4 + rr];
      __syncthreads();  // ush reads complete -> R1 reusable as cs
    }

    if (t < 32) csumsh[t] = 0.f;

    // ---- softmax over j (register path; reduce across quads) ----
    float cc[2][2][4];
    #pragma unroll
    for (int nt = 0; nt < 2; ++nt) {
      float m = breg[0][nt][0];
      #pragma unroll
      for (int mt = 0; mt < 2; ++mt)
        #pragma unroll
        for (int rr = 0; rr < 4; ++rr) m = fmaxf(m, breg[mt][nt][rr]);
      m = fmaxf(m, __shfl_xor(m, 16));
      m = fmaxf(m, __shfl_xor(m, 32));
      float s = 0.f;
      #pragma unroll
      for (int mt = 0; mt < 2; ++mt)
        #pragma unroll
        for (int rr = 0; rr < 4; ++rr) {
          float e = __expf(breg[mt][nt][rr] - m);
          cc[mt][nt][rr] = e; s += e;
        }
      s += __shfl_xor(s, 16);
      s += __shfl_xor(s, 32);
      const float rinv = 1.f / s;
      const int ii = w * 32 + nt * 16 + l15;
      #pragma unroll
      for (int mt = 0; mt < 2; ++mt)
        #pragma unroll
        for (int rr = 0; rr < 4; ++rr) {
          const float cv = cc[mt][nt][rr] * rinv;
          cc[mt][nt][rr] = cv;
          R1[(mt * 16 + quad * 4 + rr) * 264 + ii] = (_Float16)cv;
        }
    }
    __syncthreads();  // cs + csum zeros visible

    // ---- csum[j] += partials (from registers) ----
    #pragma unroll
    for (int mt = 0; mt < 2; ++mt)
      #pragma unroll
      for (int rr = 0; rr < 4; ++rr) {
        float pj = cc[mt][0][rr] + cc[mt][1][rr];
        pj += __shfl_xor(pj, 1);
        pj += __shfl_xor(pj, 2);
        pj += __shfl_xor(pj, 4);
        pj += __shfl_xor(pj, 8);
        if (l15 == 0) atomicAdd(&csumsh[mt * 16 + quad * 4 + rr], pj);
      }

    // ---- y[j,c] = sum_i c[j,i] * x16[c,i] -> R2 (fp16) ----
    {
      f32x4 acy[2][2];
      #pragma unroll
      for (int mt = 0; mt < 2; ++mt)
        #pragma unroll
        for (int nt = 0; nt < 2; ++nt) acy[mt][nt] = (f32x4){0.f, 0.f, 0.f, 0.f};
      const int cbase = w * 32;
      for (int k0 = 0; k0 < 256; k0 += 32) {
        const int ko = k0 + quad * 8;
        f16x8 a0 = *reinterpret_cast<const f16x8*>(&R1[l15 * 264 + ko]);
        f16x8 a1 = *reinterpret_cast<const f16x8*>(&R1[(16 + l15) * 264 + ko]);
        #pragma unroll
        for (int nt = 0; nt < 2; ++nt) {
          const int cp = cbase + nt * 16 + l15;
          f16x8 bf = *reinterpret_cast<const f16x8*>(&xob[cp * 256 + ko]);
          acy[0][nt] = __builtin_amdgcn_mfma_f32_16x16x32_f16(a0, bf, acy[0][nt], 0, 0, 0);
          acy[1][nt] = __builtin_amdgcn_mfma_f32_16x16x32_f16(a1, bf, acy[1][nt], 0, 0, 0);
        }
      }
      #pragma unroll
      for (int mt = 0; mt < 2; ++mt)
        #pragma unroll
        for (int nt = 0; nt < 2; ++nt) {
          const int cp = cbase + nt * 16 + l15;
          #pragma unroll
          for (int rr = 0; rr < 4; ++rr)
            R2[(mt * 16 + quad * 4 + rr) * 264 + cp] = (_Float16)acy[mt][nt][rr];
        }
    }
    __syncthreads();  // ysh + csum complete

    // ---- s[jj, dg+16k] = W16[jj*64+d,:] . y[jj,:] + bias*csum  (VALU, W from L2) ----
    const int jj = t >> 4, dg = t & 15;
    float sv[4] = {0.f, 0.f, 0.f, 0.f};
    {
      const _Float16* ysr = &R2[jj * 264];
      const _Float16* wb0 = W16 + ((size_t)jj * 64 + dg) * 256;
      for (int c0 = 0; c0 < 256; c0 += 8) {
        f16x8 yv = *reinterpret_cast<const f16x8*>(&ysr[c0]);
        #pragma unroll
        for (int k = 0; k < 4; ++k) {
          f16x8 wv = *reinterpret_cast<const f16x8*>(&wb0[k * 4096 + c0]);
          #pragma unroll
          for (int e = 0; e < 8; ++e) sv[k] += (float)yv[e] * (float)wv[e];
        }
      }
      const float cz = csumsh[jj];
      #pragma unroll
      for (int k = 0; k < 4; ++k) sv[k] += bias[jj * 64 + dg + 16 * k] * cz;
    }
    __syncthreads();  // all ysh reads done -> R2 reusable as vsh

    // ---- squash ----
    float n2 = sv[0] * sv[0] + sv[1] * sv[1] + sv[2] * sv[2] + sv[3] * sv[3];
    n2 += __shfl_xor(n2, 1);
    n2 += __shfl_xor(n2, 2);
    n2 += __shfl_xor(n2, 4);
    n2 += __shfl_xor(n2, 8);
    const float sc = sqrtf(n2) / (1.f + n2);

    if (r == 2) {
      float* vp = vout + ((size_t)b * 32 + jj) * 64 + dg;
      #pragma unroll
      for (int k = 0; k < 4; ++k) vp[16 * k] = sv[k] * sc;
    } else {
      float vbp = 0.f;
      #pragma unroll
      for (int k = 0; k < 4; ++k) {
        const float vk = sv[k] * sc;
        vsh[jj * 68 + dg + 16 * k] = vk;
        vbp += vk * bias[jj * 64 + dg + 16 * k];
      }
      vbp += __shfl_xor(vbp, 1);
      vbp += __shfl_xor(vbp, 2);
      vbp += __shfl_xor(vbp, 4);
      vbp += __shfl_xor(vbp, 8);
      if (dg == 0) vbs[jj] = vbp;
      __syncthreads();  // vsh visible

      // ---- u[j,c] = sum_d v[j,d] * WT16[j*256+c, d] -> R1 (ush) ----
      const int c = t & 255, jh = (t >> 8) * 16;
      for (int m2 = 0; m2 < 16; ++m2) {
        const int j2 = jh + m2;
        const float* vr = &vsh[j2 * 68];
        const _Float16* wtr = WT16 + ((size_t)j2 * 256 + c) * 64;
        float ua = 0.f;
        #pragma unroll
        for (int d0 = 0; d0 < 64; d0 += 8) {
          f16x8 wv2 = *reinterpret_cast<const f16x8*>(&wtr[d0]);
          #pragma unroll
          for (int e = 0; e < 8; ++e) ua += vr[d0 + e] * (float)wv2[e];
        }
        R1[j2 * 264 + c] = (_Float16)ua;
      }
      __syncthreads();  // ush visible for next iteration's delta
    }
  }
}

// ---------------------------------------------------------------------------
extern "C" void kernel_launch(void* const* d_in, const int* in_sizes, int n_in,
                              void* d_out, int out_size, void* d_ws, size_t ws_size,
                              hipStream_t stream) {
  (void)in_sizes; (void)n_in; (void)out_size; (void)ws_size;
  const float* x      = (const float*)d_in[0];
  const float* W      = (const float*)d_in[1];
  const float* bias   = (const float*)d_in[2];
  const float* b_init = (const float*)d_in[3];
  char* ws = (char*)d_ws;

  _Float16* x16  = (_Float16*)(ws);                 // 32 MiB
  _Float16* xT16 = (_Float16*)(ws + (32u << 20));   // 32 MiB
  _Float16* W16  = (_Float16*)(ws + (64u << 20));   // 1 MiB
  _Float16* WT16 = (_Float16*)(ws + (65u << 20));   // 1 MiB
  float*    vout = (float*)d_out;

  prep_w<<<512, 256, 0, stream>>>(W, W16, WT16);
  caps_routing<<<BSZ, 512, 0, stream>>>(x, bias, b_init, W16, WT16,
                                        x16, xT16, vout);
}

// Round 6
// 205.519 us; speedup vs baseline: 3.6002x; 2.0908x over previous
//
#include <hip/hip_runtime.h>

// CapsNet dynamic routing — per-batch blocks, 2 launches, no grid sync.
//   prep_w: W fp32 -> Wp[j][32 g][64 d] (f16x8 packed over c, for s-phase)
//                  -> Wd[j][8 h][256 c] (f16x8 packed over d, for u-phase)
//   caps_routing: grid 256 (block = batch), block 1024 (16 waves, 4/SIMD).
//     Converts its x slice to fp16 (both orientations), then 3 iterations:
//       delta = u@xT (MFMA) ; b += delta+vb   (b in registers, D-layout)
//       softmax over j (register shfl) ; c -> LDS ; y = c@x (MFMA) -> LDS
//       s[j,d] = dot(Wp[j,:,d], y[j,:]) via v_dot2 (lane=d, coalesced)
//       v = squash(s) ; u[j,c] = dot(Wd[j,:,c], v[j,:]) via v_dot2 (lane=c)
//     W streams from L2 (2 MB resident/XCD), ~2 MB/block/iter, coalesced.

#define BSZ 256
#define CDIM 256
#define IDIM 256
#define JDIM 32
#define DDIM 64

typedef _Float16 f16x8 __attribute__((ext_vector_type(8)));
typedef _Float16 f16x4 __attribute__((ext_vector_type(4)));
typedef _Float16 f16x2 __attribute__((ext_vector_type(2)));
typedef float f32x4 __attribute__((ext_vector_type(4)));

__device__ __forceinline__ float dot8(f16x8 a, f16x8 b, float acc) {
#if __has_builtin(__builtin_amdgcn_fdot2)
  acc = __builtin_amdgcn_fdot2(__builtin_shufflevector(a, a, 0, 1),
                               __builtin_shufflevector(b, b, 0, 1), acc, false);
  acc = __builtin_amdgcn_fdot2(__builtin_shufflevector(a, a, 2, 3),
                               __builtin_shufflevector(b, b, 2, 3), acc, false);
  acc = __builtin_amdgcn_fdot2(__builtin_shufflevector(a, a, 4, 5),
                               __builtin_shufflevector(b, b, 4, 5), acc, false);
  acc = __builtin_amdgcn_fdot2(__builtin_shufflevector(a, a, 6, 7),
                               __builtin_shufflevector(b, b, 6, 7), acc, false);
#else
  #pragma unroll
  for (int e = 0; e < 8; ++e) acc += (float)a[e] * (float)b[e];
#endif
  return acc;
}

// ---------------------------------------------------------------------------
// prep_w: grid 32 (block = j), block 256. Stage W_j in LDS, emit both packs.
// ---------------------------------------------------------------------------
__global__ __launch_bounds__(256) void prep_w(
    const float* __restrict__ W,   // [JDIM*DDIM][CDIM]
    _Float16* __restrict__ Wp,     // [(j*32+g)*64+d] f16x8 over c=8g..8g+7
    _Float16* __restrict__ Wd)     // [(j*8+h)*256+c] f16x8 over d=8h..8h+7
{
  __shared__ __align__(16) float Wsh[64 * 260];
  const int j = blockIdx.x, t = threadIdx.x;

  #pragma unroll
  for (int k = 0; k < 16; ++k) {               // 4096 float4
    const int q = k * 256 + t;
    const int row = q >> 6, c4 = (q & 63) * 4;
    *reinterpret_cast<f32x4*>(&Wsh[row * 260 + c4]) =
        *reinterpret_cast<const f32x4*>(&W[((size_t)j * 64 + row) * 256 + c4]);
  }
  __syncthreads();

  // Wp: element (g, d) = f16 pack of Wsh[d][8g..8g+7]
  {
    const int d = t & 63;
    f16x8* out = reinterpret_cast<f16x8*>(Wp) + (size_t)j * 2048;
    #pragma unroll
    for (int k = 0; k < 8; ++k) {
      const int g = (t >> 6) + 4 * k;
      f32x4 a = *reinterpret_cast<const f32x4*>(&Wsh[d * 260 + 8 * g]);
      f32x4 bq = *reinterpret_cast<const f32x4*>(&Wsh[d * 260 + 8 * g + 4]);
      f16x8 h;
      h[0] = (_Float16)a[0]; h[1] = (_Float16)a[1];
      h[2] = (_Float16)a[2]; h[3] = (_Float16)a[3];
      h[4] = (_Float16)bq[0]; h[5] = (_Float16)bq[1];
      h[6] = (_Float16)bq[2]; h[7] = (_Float16)bq[3];
      out[g * 64 + d] = h;
    }
  }
  // Wd: element (h, c) = f16 pack of Wsh[8h..8h+7][c]
  {
    const int c = t;
    f16x8* out = reinterpret_cast<f16x8*>(Wd) + (size_t)j * 2048;
    #pragma unroll
    for (int h = 0; h < 8; ++h) {
      f16x8 hh;
      #pragma unroll
      for (int e = 0; e < 8; ++e) hh[e] = (_Float16)Wsh[(8 * h + e) * 260 + c];
      out[h * 256 + c] = hh;
    }
  }
}

// ---------------------------------------------------------------------------
__global__ __launch_bounds__(1024) void caps_routing(
    const float* __restrict__ x,       // [BSZ][CDIM][IDIM] fp32
    const float* __restrict__ bias,    // [JDIM*DDIM] fp32
    const float* __restrict__ b_init,  // [BSZ][JDIM][IDIM] fp32
    const _Float16* __restrict__ Wp,
    const _Float16* __restrict__ Wd,
    _Float16* __restrict__ x16,        // ws [BSZ][CDIM][IDIM]
    _Float16* __restrict__ xT16,       // ws [BSZ][IDIM][CDIM]
    float* __restrict__ vout)          // [BSZ][JDIM][DDIM]
{
  __shared__ __align__(16) _Float16 csA[JDIM * 264];   // c (softmax out, y A-frag)
  __shared__ __align__(16) _Float16 ushA[JDIM * 264];  // u (delta A-frag)
  __shared__ __align__(16) _Float16 ysh[JDIM * 264];   // y (s-phase input)
  __shared__ __align__(16) _Float16 vsh16[JDIM * 64];  // v (u-phase input)
  __shared__ float csumsh[JDIM];
  __shared__ float vbs[JDIM];

  const int b = blockIdx.x, t = threadIdx.x;
  const int w = t >> 6, lane = t & 63, l15 = lane & 15, quad = lane >> 4;

  // ---- convert own x slice to fp16, both orientations ----
  {
    const float* xb = x + (size_t)b * 65536;
    _Float16* xo = x16 + (size_t)b * 65536;
    _Float16* xto = xT16 + (size_t)b * 65536;
    const int c4 = (t & 15) * 4, i4 = (t >> 4) * 4;
    #pragma unroll
    for (int q = 0; q < 4; ++q) {
      const int c0 = q * 64 + c4;
      f32x4 v[4];
      #pragma unroll
      for (int s = 0; s < 4; ++s)
        v[s] = *reinterpret_cast<const f32x4*>(&xb[(c0 + s) * 256 + i4]);
      #pragma unroll
      for (int s = 0; s < 4; ++s) {
        f16x4 h;
        h[0] = (_Float16)v[s][0]; h[1] = (_Float16)v[s][1];
        h[2] = (_Float16)v[s][2]; h[3] = (_Float16)v[s][3];
        *reinterpret_cast<f16x4*>(&xo[(c0 + s) * 256 + i4]) = h;
      }
      #pragma unroll
      for (int m = 0; m < 4; ++m) {
        f16x4 h;
        h[0] = (_Float16)v[0][m]; h[1] = (_Float16)v[1][m];
        h[2] = (_Float16)v[2][m]; h[3] = (_Float16)v[3][m];
        *reinterpret_cast<f16x4*>(&xto[(i4 + m) * 256 + c0]) = h;
      }
    }
  }

  // ---- b -> registers, D-layout: j = mt*16+quad*4+rr, ii = w*16+l15 ----
  float breg[2][4];
  {
    const float* bp = b_init + (size_t)b * 8192;
    #pragma unroll
    for (int mt = 0; mt < 2; ++mt)
      #pragma unroll
      for (int rr = 0; rr < 4; ++rr)
        breg[mt][rr] = bp[(mt * 16 + quad * 4 + rr) * 256 + w * 16 + l15];
  }
  __syncthreads();

  const _Float16* xob = x16 + (size_t)b * 65536;
  const _Float16* xtb = xT16 + (size_t)b * 65536;
  const f16x8* WpB = reinterpret_cast<const f16x8*>(Wp);
  const f16x8* WdB = reinterpret_cast<const f16x8*>(Wd);

  for (int r = 0; r < 3; ++r) {
    if (r) {
      // ---- delta[j,ii] = sum_c u[j,c] * xT[ii,c] ----
      f32x4 acc[2];
      acc[0] = (f32x4){0.f, 0.f, 0.f, 0.f};
      acc[1] = (f32x4){0.f, 0.f, 0.f, 0.f};
      const int ii = w * 16 + l15;
      for (int k0 = 0; k0 < 256; k0 += 32) {
        const int ko = k0 + quad * 8;
        f16x8 a0 = *reinterpret_cast<const f16x8*>(&ushA[l15 * 264 + ko]);
        f16x8 a1 = *reinterpret_cast<const f16x8*>(&ushA[(16 + l15) * 264 + ko]);
        f16x8 bf = *reinterpret_cast<const f16x8*>(&xtb[ii * 256 + ko]);
        acc[0] = __builtin_amdgcn_mfma_f32_16x16x32_f16(a0, bf, acc[0], 0, 0, 0);
        acc[1] = __builtin_amdgcn_mfma_f32_16x16x32_f16(a1, bf, acc[1], 0, 0, 0);
      }
      #pragma unroll
      for (int mt = 0; mt < 2; ++mt)
        #pragma unroll
        for (int rr = 0; rr < 4; ++rr)
          breg[mt][rr] += acc[mt][rr] + vbs[mt * 16 + quad * 4 + rr];
    }

    if (t < 32) csumsh[t] = 0.f;

    // ---- softmax over j (registers + shfl across quads) ----
    float cc[2][4];
    {
      float m = breg[0][0];
      #pragma unroll
      for (int mt = 0; mt < 2; ++mt)
        #pragma unroll
        for (int rr = 0; rr < 4; ++rr) m = fmaxf(m, breg[mt][rr]);
      m = fmaxf(m, __shfl_xor(m, 16));
      m = fmaxf(m, __shfl_xor(m, 32));
      float s = 0.f;
      #pragma unroll
      for (int mt = 0; mt < 2; ++mt)
        #pragma unroll
        for (int rr = 0; rr < 4; ++rr) {
          float e = __expf(breg[mt][rr] - m);
          cc[mt][rr] = e; s += e;
        }
      s += __shfl_xor(s, 16);
      s += __shfl_xor(s, 32);
      const float rinv = 1.f / s;
      const int ii = w * 16 + l15;
      #pragma unroll
      for (int mt = 0; mt < 2; ++mt)
        #pragma unroll
        for (int rr = 0; rr < 4; ++rr) {
          const float cv = cc[mt][rr] * rinv;
          cc[mt][rr] = cv;
          csA[(mt * 16 + quad * 4 + rr) * 264 + ii] = (_Float16)cv;
        }
    }
    __syncthreads();  // csA visible, csumsh zeroed

    // ---- csum[j] atomics ----
    #pragma unroll
    for (int mt = 0; mt < 2; ++mt)
      #pragma unroll
      for (int rr = 0; rr < 4; ++rr) {
        float pj = cc[mt][rr];
        pj += __shfl_xor(pj, 1);
        pj += __shfl_xor(pj, 2);
        pj += __shfl_xor(pj, 4);
        pj += __shfl_xor(pj, 8);
        if (l15 == 0) atomicAdd(&csumsh[mt * 16 + quad * 4 + rr], pj);
      }

    // ---- y[j,c] = sum_i c[j,i] * x16[c,i] -> ysh ----
    {
      f32x4 acy[2];
      acy[0] = (f32x4){0.f, 0.f, 0.f, 0.f};
      acy[1] = (f32x4){0.f, 0.f, 0.f, 0.f};
      const int cp = w * 16 + l15;
      for (int k0 = 0; k0 < 256; k0 += 32) {
        const int ko = k0 + quad * 8;
        f16x8 a0 = *reinterpret_cast<const f16x8*>(&csA[l15 * 264 + ko]);
        f16x8 a1 = *reinterpret_cast<const f16x8*>(&csA[(16 + l15) * 264 + ko]);
        f16x8 bf = *reinterpret_cast<const f16x8*>(&xob[cp * 256 + ko]);
        acy[0] = __builtin_amdgcn_mfma_f32_16x16x32_f16(a0, bf, acy[0], 0, 0, 0);
        acy[1] = __builtin_amdgcn_mfma_f32_16x16x32_f16(a1, bf, acy[1], 0, 0, 0);
      }
      #pragma unroll
      for (int mt = 0; mt < 2; ++mt)
        #pragma unroll
        for (int rr = 0; rr < 4; ++rr)
          ysh[(mt * 16 + quad * 4 + rr) * 264 + cp] = (_Float16)acy[mt][rr];
    }
    __syncthreads();  // ysh + csumsh complete

    // ---- per-j s / squash / u (wave w owns j = w, w+16) ----
    for (int jj = w; jj < 32; jj += 16) {
      const float biasv = bias[jj * 64 + lane];
      const f16x8* wrow = WpB + (size_t)jj * 2048 + lane;   // + g*64
      const _Float16* yr = &ysh[jj * 264];
      float sacc = 0.f;
      #pragma unroll 4
      for (int g = 0; g < 32; ++g)
        sacc = dot8(wrow[g * 64], *reinterpret_cast<const f16x8*>(&yr[g * 8]), sacc);
      sacc += biasv * csumsh[jj];

      float n2 = sacc * sacc;
      n2 += __shfl_xor(n2, 1);
      n2 += __shfl_xor(n2, 2);
      n2 += __shfl_xor(n2, 4);
      n2 += __shfl_xor(n2, 8);
      n2 += __shfl_xor(n2, 16);
      n2 += __shfl_xor(n2, 32);
      const float sc = sqrtf(n2) / (1.f + n2);
      const float vv = sacc * sc;

      if (r == 2) {
        vout[((size_t)b * 32 + jj) * 64 + lane] = vv;
      } else {
        vsh16[jj * 64 + lane] = (_Float16)vv;
        float vbp = vv * biasv;
        vbp += __shfl_xor(vbp, 1);
        vbp += __shfl_xor(vbp, 2);
        vbp += __shfl_xor(vbp, 4);
        vbp += __shfl_xor(vbp, 8);
        vbp += __shfl_xor(vbp, 16);
        vbp += __shfl_xor(vbp, 32);
        if (lane == 0) vbs[jj] = vbp;

        // u[jj, c] = sum_d v[jj,d] * W[jj,d,c]   (lane = c base)
        float ua[4] = {0.f, 0.f, 0.f, 0.f};
        const f16x8* wd = WdB + (size_t)jj * 2048;
        #pragma unroll
        for (int h = 0; h < 8; ++h) {
          f16x8 vvv = *reinterpret_cast<const f16x8*>(&vsh16[jj * 64 + h * 8]);
          #pragma unroll
          for (int k = 0; k < 4; ++k)
            ua[k] = dot8(wd[h * 256 + lane + 64 * k], vvv, ua[k]);
        }
        #pragma unroll
        for (int k = 0; k < 4; ++k)
          ushA[jj * 264 + lane + 64 * k] = (_Float16)ua[k];
      }
    }
    if (r < 2) __syncthreads();  // ushA + vbs visible; csA/ysh reusable
  }
}

// ---------------------------------------------------------------------------
extern "C" void kernel_launch(void* const* d_in, const int* in_sizes, int n_in,
                              void* d_out, int out_size, void* d_ws, size_t ws_size,
                              hipStream_t stream) {
  (void)in_sizes; (void)n_in; (void)out_size; (void)ws_size;
  const float* x      = (const float*)d_in[0];
  const float* W      = (const float*)d_in[1];
  const float* bias   = (const float*)d_in[2];
  const float* b_init = (const float*)d_in[3];
  char* ws = (char*)d_ws;

  _Float16* x16  = (_Float16*)(ws);                 // 32 MiB
  _Float16* xT16 = (_Float16*)(ws + (32u << 20));   // 32 MiB
  _Float16* Wp   = (_Float16*)(ws + (64u << 20));   // 1 MiB
  _Float16* Wd   = (_Float16*)(ws + (65u << 20));   // 1 MiB
  float*    vout = (float*)d_out;

  prep_w<<<32, 256, 0, stream>>>(W, Wp, Wd);
  caps_routing<<<BSZ, 1024, 0, stream>>>(x, bias, b_init, Wp, Wd,
                                         x16, xT16, vout);
}